// Round 1
// baseline (4250.709 us; speedup 1.0000x reference)
//
#include <hip/hip_runtime.h>

typedef long long i64;

#define Bv 8
#define Nv 1024
#define Dv 768
#define Hh 4
#define DKv 192

// ---------------------------------------------------------------------------
// Generic batched f32 GEMM: C[z] = op(A[z] @ B[z] + bias[z])
// Tile 64x64, K-step 16, 256 threads, 4x4 per thread.
// All of M, N divisible by 64 and K divisible by 16 in every use here.
// flags: 0 -> C = acc + bias (bias may be null)
//        1 -> C += relu(acc + bias)   (read-modify-write)
// ---------------------------------------------------------------------------
__global__ __launch_bounds__(256) void gemm_f32(
    const float* __restrict__ A, i64 sA, int lda,
    const float* __restrict__ Bm, i64 sB, int ldb,
    const float* __restrict__ bias, i64 sBias,
    float* __restrict__ C, i64 sC, int ldc,
    int K, int flags)
{
    const int z = blockIdx.z;
    A  += (i64)z * sA;
    Bm += (i64)z * sB;
    C  += (i64)z * sC;
    if (bias) bias += (i64)z * sBias;

    const int bm = blockIdx.y * 64;
    const int bn = blockIdx.x * 64;
    const int tid = threadIdx.x;
    const int tx = tid & 15, ty = tid >> 4;

    __shared__ float As[16][68];   // [k][m], pad to 68 for aligned float4 rows
    __shared__ float Bs[16][64];   // [k][n]

    float acc[4][4] = {};

    const int ar = tid >> 2;          // 0..63  (row of A tile)
    const int ac = (tid & 3) << 2;    // 0,4,8,12 (k-chunk of A tile)
    const int br = tid >> 4;          // 0..15  (k-row of B tile)
    const int bc = (tid & 15) << 2;   // 0..60  (n-chunk of B tile)

    for (int k0 = 0; k0 < K; k0 += 16) {
        float4 av = *(const float4*)&A[(i64)(bm + ar) * lda + k0 + ac];
        float4 bv = *(const float4*)&Bm[(i64)(k0 + br) * ldb + bn + bc];
        __syncthreads();
        As[ac + 0][ar] = av.x;
        As[ac + 1][ar] = av.y;
        As[ac + 2][ar] = av.z;
        As[ac + 3][ar] = av.w;
        *(float4*)&Bs[br][bc] = bv;
        __syncthreads();
        #pragma unroll
        for (int kk = 0; kk < 16; ++kk) {
            float a[4], b[4];
            *(float4*)a = *(const float4*)&As[kk][ty * 4];
            *(float4*)b = *(const float4*)&Bs[kk][tx * 4];
            #pragma unroll
            for (int i = 0; i < 4; ++i)
                #pragma unroll
                for (int j = 0; j < 4; ++j)
                    acc[i][j] = fmaf(a[i], b[j], acc[i][j]);
        }
    }

    float bb[4] = {0.f, 0.f, 0.f, 0.f};
    if (bias) *(float4*)bb = *(const float4*)&bias[bn + tx * 4];

    #pragma unroll
    for (int i = 0; i < 4; ++i) {
        float* cp = &C[(i64)(bm + ty * 4 + i) * ldc + bn + tx * 4];
        if (flags == 1) {
            float4 old = *(const float4*)cp;
            float4 v;
            v.x = old.x + fmaxf(acc[i][0] + bb[0], 0.f);
            v.y = old.y + fmaxf(acc[i][1] + bb[1], 0.f);
            v.z = old.z + fmaxf(acc[i][2] + bb[2], 0.f);
            v.w = old.w + fmaxf(acc[i][3] + bb[3], 0.f);
            *(float4*)cp = v;
        } else {
            float4 v;
            v.x = acc[i][0] + bb[0];
            v.y = acc[i][1] + bb[1];
            v.z = acc[i][2] + bb[2];
            v.w = acc[i][3] + bb[3];
            *(float4*)cp = v;
        }
    }
}

// ---------------------------------------------------------------------------
// Masked 3-edge scores: for (b,h), S[n,m] = (adj[b,n,m]==e+1) ? scale*q_e.k_e : ...
// accumulated over e; entries that end exactly 0 -> -1e9 (matches reference).
// Writes directly into ga region of d_out in (h,B,N,N) layout.
// ---------------------------------------------------------------------------
__global__ __launch_bounds__(256) void scores_k(
    const float* __restrict__ q, const float* __restrict__ kmat,
    const int* __restrict__ adj, float* __restrict__ ga)
{
    const int z = blockIdx.z;
    const int b = z >> 2, h = z & 3;
    const int m0 = blockIdx.x * 64, n0 = blockIdx.y * 64;
    const int tid = threadIdx.x;
    const int tx = tid & 15, ty = tid >> 4;

    __shared__ float Qs[16][68], Ks[16][68];

    const int ar = tid >> 2;
    const int ac = (tid & 3) << 2;

    int adjv[4][4];
    {
        const int* ap = adj + ((i64)b * Nv + n0) * Nv + m0;
        #pragma unroll
        for (int i = 0; i < 4; ++i)
            #pragma unroll
            for (int j = 0; j < 4; ++j)
                adjv[i][j] = ap[(i64)(ty * 4 + i) * Nv + tx * 4 + j];
    }

    float fin[4][4] = {};
    const float scale = 0.07216878364870323f;  // 1/sqrt(192)

    for (int e = 0; e < 3; ++e) {
        const float* qe = q    + (i64)e * Bv * Nv * Dv + ((i64)b * Nv + n0) * Dv + h * DKv;
        const float* ke = kmat + (i64)e * Bv * Nv * Dv + ((i64)b * Nv + m0) * Dv + h * DKv;
        float acc[4][4] = {};
        for (int k0 = 0; k0 < DKv; k0 += 16) {
            float4 qv = *(const float4*)&qe[(i64)ar * Dv + k0 + ac];
            float4 kv = *(const float4*)&ke[(i64)ar * Dv + k0 + ac];
            __syncthreads();
            Qs[ac + 0][ar] = qv.x; Qs[ac + 1][ar] = qv.y;
            Qs[ac + 2][ar] = qv.z; Qs[ac + 3][ar] = qv.w;
            Ks[ac + 0][ar] = kv.x; Ks[ac + 1][ar] = kv.y;
            Ks[ac + 2][ar] = kv.z; Ks[ac + 3][ar] = kv.w;
            __syncthreads();
            #pragma unroll
            for (int kk = 0; kk < 16; ++kk) {
                float a[4], bb[4];
                *(float4*)a  = *(const float4*)&Qs[kk][ty * 4];
                *(float4*)bb = *(const float4*)&Ks[kk][tx * 4];
                #pragma unroll
                for (int i = 0; i < 4; ++i)
                    #pragma unroll
                    for (int j = 0; j < 4; ++j)
                        acc[i][j] = fmaf(a[i], bb[j], acc[i][j]);
            }
        }
        #pragma unroll
        for (int i = 0; i < 4; ++i)
            #pragma unroll
            for (int j = 0; j < 4; ++j)
                if (adjv[i][j] == e + 1) fin[i][j] += acc[i][j] * scale;
    }

    float* op = ga + (((i64)h * Bv + b) * Nv + n0) * Nv + m0;
    #pragma unroll
    for (int i = 0; i < 4; ++i) {
        float4 o;
        o.x = (fin[i][0] == 0.f) ? -1e9f : fin[i][0];
        o.y = (fin[i][1] == 0.f) ? -1e9f : fin[i][1];
        o.z = (fin[i][2] == 0.f) ? -1e9f : fin[i][2];
        o.w = (fin[i][3] == 0.f) ? -1e9f : fin[i][3];
        *(float4*)&op[(i64)(ty * 4 + i) * Nv + tx * 4] = o;
    }
}

// ---------------------------------------------------------------------------
// In-place row softmax over the last dim (1024), one block per row.
// ---------------------------------------------------------------------------
__global__ __launch_bounds__(256) void softmax_k(float* __restrict__ ga)
{
    const i64 row = blockIdx.x;
    float* p = ga + row * (i64)Nv;
    const int tid = threadIdx.x;
    const int wid = tid >> 6, lane = tid & 63;

    float4 v = *(float4*)&p[tid * 4];
    float m = fmaxf(fmaxf(v.x, v.y), fmaxf(v.z, v.w));
    #pragma unroll
    for (int o = 32; o >= 1; o >>= 1) m = fmaxf(m, __shfl_xor(m, o));

    __shared__ float red[4];
    if (lane == 0) red[wid] = m;
    __syncthreads();
    m = fmaxf(fmaxf(red[0], red[1]), fmaxf(red[2], red[3]));

    float e0 = expf(v.x - m), e1 = expf(v.y - m), e2 = expf(v.z - m), e3 = expf(v.w - m);
    float s = e0 + e1 + e2 + e3;
    #pragma unroll
    for (int o = 32; o >= 1; o >>= 1) s += __shfl_xor(s, o);
    __syncthreads();                    // everyone done reading red (max)
    if (lane == 0) red[wid] = s;
    __syncthreads();
    s = red[0] + red[1] + red[2] + red[3];

    const float inv = 1.0f / s;
    float4 o;
    o.x = e0 * inv; o.y = e1 * inv; o.z = e2 * inv; o.w = e3 * inv;
    *(float4*)&p[tid * 4] = o;
}

// X[h,b,n,d] = nodes[b,n,d]  (broadcast over h)
__global__ __launch_bounds__(256) void xinit_k(const float* __restrict__ nodes,
                                               float* __restrict__ X)
{
    const i64 i = (i64)blockIdx.x * 256 + threadIdx.x;  // over B*N*D/4
    float4 v = ((const float4*)nodes)[i];
    const i64 q = (i64)Bv * Nv * Dv / 4;
    #pragma unroll
    for (int h = 0; h < Hh; ++h) ((float4*)X)[(i64)h * q + i] = v;
}

// cat[b,n,h*D+d] = X[h,b,n,d]
__global__ __launch_bounds__(256) void catperm_k(const float* __restrict__ X,
                                                 float* __restrict__ cat)
{
    const i64 i4 = (i64)blockIdx.x * 256 + threadIdx.x;  // over H*B*N*D/4
    const i64 i = i4 * 4;
    const int d = (int)(i % Dv);
    const i64 t = i / Dv;
    const int h = (int)(t % Hh);
    const i64 bn = t / Hh;
    float4 v = *(const float4*)&X[((i64)h * Bv * Nv + bn) * Dv + d];
    ((float4*)cat)[i4] = v;
}

// ---------------------------------------------------------------------------
extern "C" void kernel_launch(void* const* d_in, const int* in_sizes, int n_in,
                              void* d_out, int out_size, void* d_ws, size_t ws_size,
                              hipStream_t stream)
{
    const float* nodes = (const float*)d_in[0];
    const int*   adj   = (const int*)d_in[1];
    const float* Wq    = (const float*)d_in[2];
    const float* bq    = (const float*)d_in[3];
    const float* Wk    = (const float*)d_in[4];
    const float* bk    = (const float*)d_in[5];
    const float* gcnW  = (const float*)d_in[6];
    const float* gcnb  = (const float*)d_in[7];
    const float* Wagg  = (const float*)d_in[8];
    const float* bagg  = (const float*)d_in[9];

    float* out = (float*)d_out;                       // (B,N,D)
    float* ga  = out + (i64)Bv * Nv * Dv;             // (H,B,N,N)

    const i64 BND  = (i64)Bv * Nv * Dv;               // 6,291,456
    const i64 HBND = (i64)Hh * BND;                   // 25,165,824

    // phase 1: q (3*BND), k (3*BND); phase 2 (after scores): X (HBND), H (HBND)
    float* q    = (float*)d_ws;
    float* kbuf = q + 3 * BND;
    float* X    = (float*)d_ws;
    float* Hbuf = X + HBND;

    dim3 blk(256);

    // Q/K projections: batched over 3 edges
    gemm_f32<<<dim3(Dv / 64, (Bv * Nv) / 64, 3), blk, 0, stream>>>(
        nodes, 0, Dv, Wq, (i64)Dv * Dv, Dv, bq, Dv, q, BND, Dv, Dv, 0);
    gemm_f32<<<dim3(Dv / 64, (Bv * Nv) / 64, 3), blk, 0, stream>>>(
        nodes, 0, Dv, Wk, (i64)Dv * Dv, Dv, bk, Dv, kbuf, BND, Dv, Dv, 0);

    // masked edge-typed scores -> ga region
    scores_k<<<dim3(Nv / 64, Nv / 64, Bv * Hh), blk, 0, stream>>>(q, kbuf, adj, ga);

    // softmax in place (rows = H*B*N)
    softmax_k<<<dim3(Hh * Bv * Nv), blk, 0, stream>>>(ga);

    // X = broadcast(nodes) over heads
    xinit_k<<<dim3((unsigned)(BND / 4 / 256)), blk, 0, stream>>>(nodes, X);

    // 2 GCN iterations
    for (int it = 0; it < 2; ++it) {
        // H = X @ gcn_W[it]
        gemm_f32<<<dim3(Dv / 64, (Hh * Bv * Nv) / 64, 1), blk, 0, stream>>>(
            X, 0, Dv, gcnW + (i64)it * Dv * Dv, 0, Dv, nullptr, 0,
            Hbuf, 0, Dv, Dv, 0);
        // X += relu(ga @ H + gcn_b[it])   (degs = softmax row-sum = 1)
        gemm_f32<<<dim3(Dv / 64, Nv / 64, Hh * Bv), blk, 0, stream>>>(
            ga, (i64)Nv * Nv, Nv, Hbuf, (i64)Nv * Dv, Dv,
            gcnb + (i64)it * Dv, 0, X, (i64)Nv * Dv, Dv, Nv, 1);
    }

    // cat = permute(X) into Hbuf, then out = cat @ W_agg + b_agg
    catperm_k<<<dim3((unsigned)(HBND / 4 / 256)), blk, 0, stream>>>(X, Hbuf);
    gemm_f32<<<dim3(Dv / 64, (Bv * Nv) / 64, 1), blk, 0, stream>>>(
        Hbuf, 0, Hh * Dv, Wagg, 0, Dv, bagg, 0, out, 0, Dv, Hh * Dv, 0);
}

// Round 2
// 741.368 us; speedup vs baseline: 5.7336x; 5.7336x over previous
//
#include <hip/hip_runtime.h>

typedef long long i64;
typedef unsigned short u16;
typedef __attribute__((ext_vector_type(8))) short short8;
typedef __attribute__((ext_vector_type(4))) float f32x4;

#define Bv 8
#define Nv 1024
#define Dv 768
#define Hh 4
#define DKv 192
#define BND ((i64)Bv * Nv * Dv)      /* 6,291,456  */
#define HBND ((i64)Hh * BND)         /* 25,165,824 */

__device__ __forceinline__ u16 f2bf(float f) {
    unsigned u = __builtin_bit_cast(unsigned, f);
    u += 0x7fffu + ((u >> 16) & 1u);
    return (u16)(u >> 16);
}
__device__ __forceinline__ float bf2f(u16 h) {
    unsigned u = ((unsigned)h) << 16;
    return __builtin_bit_cast(float, u);
}

// async global->LDS, 16B per lane. LDS dest must be wave-uniform base.
__device__ __forceinline__ void gl_lds16(const u16* g, u16* l) {
    __builtin_amdgcn_global_load_lds(
        (const __attribute__((address_space(1))) void*)g,
        (__attribute__((address_space(3))) void*)l, 16, 0, 0);
}

// ---------------------------------------------------------------------------
// bf16 MFMA GEMM:  C[z] = epilogue( A[z] (MxK) @ Bt[z]^T (NxK) + bias[z] )
// 128x128 tile, BK=64, 256 threads (4 waves, each a 64x64 sub-tile of 4x4
// 16x16x32 fragments). global_load_lds staging with XOR slot swizzle
// (involution applied on source AND read; LDS dest linear — rule 21).
// EPI: 0 = f32 store (+bias), 1 = bf16 store (+bias), 2 = X-update:
//      X = bf16( bf2f(X) + relu(acc + bias) )  (C is u16*, RMW)
// ---------------------------------------------------------------------------
template <int EPI>
__global__ __launch_bounds__(256) void gemm_bf16(
    const u16* __restrict__ A, i64 sA, int lda,
    const u16* __restrict__ Bt, i64 sBt, int ldbt,
    const float* __restrict__ bias, i64 sBias,
    void* __restrict__ Cv, i64 sC, int ldc, int K)
{
    __shared__ u16 Asb[128 * 64];
    __shared__ u16 Bsb[128 * 64];

    const int z = blockIdx.z;
    A  += (i64)z * sA;
    Bt += (i64)z * sBt;
    if (bias) bias += (i64)z * sBias;

    const int bm = blockIdx.y * 128, bn = blockIdx.x * 128;
    const int tid = threadIdx.x;
    const int w = tid >> 6, l = tid & 63;
    const int wr = w >> 1, wc = w & 1;
    const int kgrp = l >> 4, lr = l & 15;

    const u16* Ab = A + (i64)bm * lda;
    const u16* Bb = Bt + (i64)bn * ldbt;

    f32x4 acc[4][4];
    #pragma unroll
    for (int i = 0; i < 4; ++i)
        #pragma unroll
        for (int j = 0; j < 4; ++j)
            acc[i][j] = (f32x4){0.f, 0.f, 0.f, 0.f};

    for (int k0 = 0; k0 < K; k0 += 64) {
        if (k0) __syncthreads();
        #pragma unroll
        for (int t = 0; t < 4; ++t) {
            const int idx = t * 256 + tid;
            const int r = idx >> 3, s = idx & 7;
            const int ss = s ^ (r & 7);
            gl_lds16(Ab + (i64)r * lda + k0 + ss * 8, &Asb[(t * 256 + w * 64) * 8]);
        }
        #pragma unroll
        for (int t = 0; t < 4; ++t) {
            const int idx = t * 256 + tid;
            const int r = idx >> 3, s = idx & 7;
            const int ss = s ^ (r & 7);
            gl_lds16(Bb + (i64)r * ldbt + k0 + ss * 8, &Bsb[(t * 256 + w * 64) * 8]);
        }
        __syncthreads();

        #pragma unroll
        for (int ks = 0; ks < 2; ++ks) {
            const int slot = ks * 4 + kgrp;   // k = ks*32 + kgrp*8
            short8 a[4], b[4];
            #pragma unroll
            for (int i = 0; i < 4; ++i) {
                const int r = wr * 64 + i * 16 + lr;
                a[i] = *(const short8*)&Asb[r * 64 + ((slot ^ (r & 7)) << 3)];
            }
            #pragma unroll
            for (int j = 0; j < 4; ++j) {
                const int r = wc * 64 + j * 16 + lr;
                b[j] = *(const short8*)&Bsb[r * 64 + ((slot ^ (r & 7)) << 3)];
            }
            #pragma unroll
            for (int i = 0; i < 4; ++i)
                #pragma unroll
                for (int j = 0; j < 4; ++j)
                    acc[i][j] = __builtin_amdgcn_mfma_f32_16x16x32_bf16(
                        a[i], b[j], acc[i][j], 0, 0, 0);
        }
    }

    float bj[4] = {0.f, 0.f, 0.f, 0.f};
    if (bias) {
        #pragma unroll
        for (int j = 0; j < 4; ++j) bj[j] = bias[bn + wc * 64 + j * 16 + lr];
    }

    #pragma unroll
    for (int i = 0; i < 4; ++i) {
        const int mbase = bm + wr * 64 + i * 16 + kgrp * 4;
        #pragma unroll
        for (int j = 0; j < 4; ++j) {
            const int n = bn + wc * 64 + j * 16 + lr;
            #pragma unroll
            for (int rg = 0; rg < 4; ++rg) {
                const i64 off = (i64)z * sC + (i64)(mbase + rg) * ldc + n;
                const float v = acc[i][j][rg] + bj[j];
                if (EPI == 0) {
                    ((float*)Cv)[off] = v;
                } else if (EPI == 1) {
                    ((u16*)Cv)[off] = f2bf(v);
                } else {
                    u16* xp = (u16*)Cv + off;
                    *xp = f2bf(bf2f(*xp) + fmaxf(v, 0.f));
                }
            }
        }
    }
}

// ---------------------------------------------------------------------------
// Fused 3-edge masked scores (MFMA). Per (b,h), 64x64 tile: S_e = q_e.k_e^T
// accumulated per edge; fin = (adj==e+1) select * scale; fin==0 -> -1e9.
// q/k bf16 in (e,B,N,768) layout, head at column offset h*192. K=192.
// ---------------------------------------------------------------------------
__global__ __launch_bounds__(256) void scores_mfma(
    const u16* __restrict__ qb, const u16* __restrict__ kb,
    const int* __restrict__ adj, float* __restrict__ ga)
{
    __shared__ u16 Qs[64 * 192];
    __shared__ u16 Ks[64 * 192];

    const int z = blockIdx.z;          // z = h*8 + b
    const int h = z >> 3, b = z & 7;
    const int m0 = blockIdx.x * 64, n0 = blockIdx.y * 64;
    const int tid = threadIdx.x;
    const int w = tid >> 6, l = tid & 63;
    const int wr = w >> 1, wc = w & 1;
    const int kgrp = l >> 4, lr = l & 15;

    f32x4 acc[3][2][2];
    #pragma unroll
    for (int e = 0; e < 3; ++e)
        #pragma unroll
        for (int i = 0; i < 2; ++i)
            #pragma unroll
            for (int j = 0; j < 2; ++j)
                acc[e][i][j] = (f32x4){0.f, 0.f, 0.f, 0.f};

    #pragma unroll
    for (int e = 0; e < 3; ++e) {
        const u16* qe = qb + (i64)e * BND + ((i64)b * Nv + n0) * Dv + h * DKv;
        const u16* ke = kb + (i64)e * BND + ((i64)b * Nv + m0) * Dv + h * DKv;
        __syncthreads();
        #pragma unroll
        for (int t = 0; t < 6; ++t) {
            const int idx = t * 256 + tid;
            const int r = idx / 24, s = idx % 24;
            const int ss = s ^ (r & 7);        // toggles low 3 bits only, stays <24
            gl_lds16(qe + (i64)r * Dv + ss * 8, &Qs[(t * 256 + w * 64) * 8]);
            gl_lds16(ke + (i64)r * Dv + ss * 8, &Ks[(t * 256 + w * 64) * 8]);
        }
        __syncthreads();
        #pragma unroll
        for (int ks = 0; ks < 6; ++ks) {
            const int slot = ks * 4 + kgrp;
            short8 a[2], bf[2];
            #pragma unroll
            for (int i = 0; i < 2; ++i) {
                const int r = wr * 32 + i * 16 + lr;
                a[i] = *(const short8*)&Qs[r * 192 + ((slot ^ (r & 7)) << 3)];
            }
            #pragma unroll
            for (int j = 0; j < 2; ++j) {
                const int r = wc * 32 + j * 16 + lr;
                bf[j] = *(const short8*)&Ks[r * 192 + ((slot ^ (r & 7)) << 3)];
            }
            #pragma unroll
            for (int i = 0; i < 2; ++i)
                #pragma unroll
                for (int j = 0; j < 2; ++j)
                    acc[e][i][j] = __builtin_amdgcn_mfma_f32_16x16x32_bf16(
                        a[i], bf[j], acc[e][i][j], 0, 0, 0);
        }
    }

    const float scale = 0.07216878364870323f;  // 1/sqrt(192)
    #pragma unroll
    for (int i = 0; i < 2; ++i) {
        const int nr0 = n0 + wr * 32 + i * 16 + kgrp * 4;
        #pragma unroll
        for (int j = 0; j < 2; ++j) {
            const int m = m0 + wc * 32 + j * 16 + lr;
            #pragma unroll
            for (int rg = 0; rg < 4; ++rg) {
                const int n = nr0 + rg;
                const int av = adj[((i64)b * Nv + n) * Nv + m];
                float fin = 0.f;
                if (av == 1) fin = acc[0][i][j][rg] * scale;
                else if (av == 2) fin = acc[1][i][j][rg] * scale;
                else if (av == 3) fin = acc[2][i][j][rg] * scale;
                if (fin == 0.f) fin = -1e9f;
                ga[((i64)z * Nv + n) * Nv + m] = fin;
            }
        }
    }
}

// in-place row softmax (1024 cols) + bf16 copy
__global__ __launch_bounds__(256) void softmax_k(float* __restrict__ ga,
                                                 u16* __restrict__ gab)
{
    const i64 row = blockIdx.x;
    float* p = ga + row * (i64)Nv;
    const int tid = threadIdx.x;
    const int wid = tid >> 6, lane = tid & 63;

    float4 v = *(float4*)&p[tid * 4];
    float m = fmaxf(fmaxf(v.x, v.y), fmaxf(v.z, v.w));
    #pragma unroll
    for (int o = 32; o >= 1; o >>= 1) m = fmaxf(m, __shfl_xor(m, o));

    __shared__ float red[4];
    if (lane == 0) red[wid] = m;
    __syncthreads();
    m = fmaxf(fmaxf(red[0], red[1]), fmaxf(red[2], red[3]));

    float e0 = expf(v.x - m), e1 = expf(v.y - m), e2 = expf(v.z - m), e3 = expf(v.w - m);
    float s = e0 + e1 + e2 + e3;
    #pragma unroll
    for (int o = 32; o >= 1; o >>= 1) s += __shfl_xor(s, o);
    __syncthreads();
    if (lane == 0) red[wid] = s;
    __syncthreads();
    s = red[0] + red[1] + red[2] + red[3];

    const float inv = 1.0f / s;
    float4 o;
    o.x = e0 * inv; o.y = e1 * inv; o.z = e2 * inv; o.w = e3 * inv;
    *(float4*)&p[tid * 4] = o;

    ushort4 ob;
    ob.x = f2bf(o.x); ob.y = f2bf(o.y); ob.z = f2bf(o.z); ob.w = f2bf(o.w);
    *(ushort4*)&gab[row * (i64)Nv + tid * 4] = ob;
}

// f32 -> bf16, 4 per thread
__global__ __launch_bounds__(256) void cvt_bf16_k(const float* __restrict__ in,
                                                  u16* __restrict__ out)
{
    const i64 i = (i64)blockIdx.x * 256 + threadIdx.x;
    float4 v = ((const float4*)in)[i];
    ushort4 o;
    o.x = f2bf(v.x); o.y = f2bf(v.y); o.z = f2bf(v.z); o.w = f2bf(v.w);
    ((ushort4*)out)[i] = o;
}

// batched transpose + bf16: in (R x C f32, stride sIn) -> out (C x R bf16, stride sOut)
__global__ __launch_bounds__(256) void transpose_bf16(
    const float* __restrict__ in, i64 sIn, u16* __restrict__ out, i64 sOut,
    int R, int C)
{
    __shared__ u16 t[32][33];
    const int z = blockIdx.z;
    in += (i64)z * sIn;
    out += (i64)z * sOut;
    const int c0 = blockIdx.x * 32, r0 = blockIdx.y * 32;
    const int tx = threadIdx.x & 31, ty = threadIdx.x >> 5;
    #pragma unroll
    for (int i = ty; i < 32; i += 8)
        t[i][tx] = f2bf(in[(i64)(r0 + i) * C + c0 + tx]);
    __syncthreads();
    #pragma unroll
    for (int i = ty; i < 32; i += 8)
        out[(i64)(c0 + i) * R + r0 + tx] = t[tx][i];
}

// X_bf16[h,b,n,d] = bf16(nodes[b,n,d])
__global__ __launch_bounds__(256) void xinit_k(const float* __restrict__ nodes,
                                               u16* __restrict__ Xb)
{
    const i64 i = (i64)blockIdx.x * 256 + threadIdx.x;  // over BND/4
    float4 v = ((const float4*)nodes)[i];
    ushort4 o;
    o.x = f2bf(v.x); o.y = f2bf(v.y); o.z = f2bf(v.z); o.w = f2bf(v.w);
    const i64 q4 = BND / 4;
    #pragma unroll
    for (int h = 0; h < Hh; ++h) ((ushort4*)Xb)[(i64)h * q4 + i] = o;
}

// cat[b,n,h*768+d] = X_bf16[h,b,n,d]  (16B per thread)
__global__ __launch_bounds__(256) void catperm_k(const u16* __restrict__ Xb,
                                                 u16* __restrict__ cat)
{
    const i64 i8 = (i64)blockIdx.x * 256 + threadIdx.x;  // over HBND/8
    const i64 i = i8 * 8;
    const int d = (int)(i % Dv);
    const i64 t = i / Dv;
    const int h = (int)(t & 3);
    const i64 bn = t >> 2;
    const int4 v = *(const int4*)&Xb[(i64)h * BND + bn * Dv + d];
    ((int4*)cat)[i8] = v;
}

// ---------------------------------------------------------------------------
extern "C" void kernel_launch(void* const* d_in, const int* in_sizes, int n_in,
                              void* d_out, int out_size, void* d_ws, size_t ws_size,
                              hipStream_t stream)
{
    const float* nodes = (const float*)d_in[0];
    const int*   adj   = (const int*)d_in[1];
    const float* Wq    = (const float*)d_in[2];
    const float* bq    = (const float*)d_in[3];
    const float* Wk    = (const float*)d_in[4];
    const float* bk    = (const float*)d_in[5];
    const float* gcnW  = (const float*)d_in[6];
    const float* gcnb  = (const float*)d_in[7];
    const float* Wagg  = (const float*)d_in[8];
    const float* bagg  = (const float*)d_in[9];

    float* out = (float*)d_out;             // (B,N,D) f32
    float* gaf = out + BND;                 // (H,B,N,N) f32

    const i64 W768 = (i64)768 * 768;
    u16* ws     = (u16*)d_ws;
    u16* qb     = ws;                       // 3*BND          (phase 1)
    u16* kb2    = ws + 3 * BND;             // 3*BND          (phase 1)
    u16* gab    = ws;                       // H*B*N*N bf16   (aliases q/k after scores)
    u16* nodesb = ws + 6 * BND;             // BND
    u16* gcnWt  = nodesb + BND;             // 2*W768
    u16* waggt  = gcnWt + 2 * W768;         // 768*3072
    u16* Xb     = waggt + (i64)768 * 3072;  // HBND
    u16* Htb    = Xb + HBND;                // HBND  (H^T; later cat)
    u16* wqt    = Htb;                      // 3*W768 (alias, dead before Ht)
    u16* wkt    = Htb + 3 * W768;           // 3*W768
    u16* catb   = Htb;                      // alias after last Xupd

    dim3 blk(256);

    cvt_bf16_k<<<dim3((unsigned)(BND / 4 / 256)), blk, 0, stream>>>(nodes, nodesb);

    transpose_bf16<<<dim3(24, 24, 3), blk, 0, stream>>>(Wq, W768, wqt, W768, 768, 768);
    transpose_bf16<<<dim3(24, 24, 3), blk, 0, stream>>>(Wk, W768, wkt, W768, 768, 768);
    transpose_bf16<<<dim3(24, 24, 2), blk, 0, stream>>>(gcnW, W768, gcnWt, W768, 768, 768);
    transpose_bf16<<<dim3(24, 96, 1), blk, 0, stream>>>(Wagg, 0, waggt, 0, 3072, 768);

    // q/k projections (bf16 out, +bias), batched over 3 edges
    gemm_bf16<1><<<dim3(6, 64, 3), blk, 0, stream>>>(
        nodesb, 0, Dv, wqt, W768, Dv, bq, Dv, qb, BND, Dv, Dv);
    gemm_bf16<1><<<dim3(6, 64, 3), blk, 0, stream>>>(
        nodesb, 0, Dv, wkt, W768, Dv, bk, Dv, kb2, BND, Dv, Dv);

    // fused masked scores -> ga f32 (d_out region)
    scores_mfma<<<dim3(16, 16, 32), blk, 0, stream>>>(qb, kb2, adj, gaf);

    // softmax in place + bf16 copy (gab aliases q/k, both dead now)
    softmax_k<<<dim3(Hh * Bv * Nv), blk, 0, stream>>>(gaf, gab);

    xinit_k<<<dim3((unsigned)(BND / 4 / 256)), blk, 0, stream>>>(nodes, Xb);

    for (int it = 0; it < 2; ++it) {
        // H^T = gcnW[it]^T @ X^T : A = gcnWt (768x768), Bt = Xb (32768x768)
        gemm_bf16<1><<<dim3(256, 6, 1), blk, 0, stream>>>(
            gcnWt + (i64)it * W768, 0, Dv, Xb, 0, Dv, nullptr, 0,
            Htb, 0, 32768, Dv);
        // X += relu(ga @ H + b) : A = gab[z] (1024x1024), Bt = Ht[:, z*1024:]
        gemm_bf16<2><<<dim3(6, 8, 32), blk, 0, stream>>>(
            gab, (i64)Nv * Nv, Nv, Htb, 1024, 32768, gcnb + (i64)it * Dv, 0,
            Xb, (i64)Nv * Dv, Dv, Nv);
    }

    catperm_k<<<dim3((unsigned)(HBND / 8 / 256)), blk, 0, stream>>>(Xb, catb);

    // out = cat @ W_agg + b_agg (f32 out)
    gemm_bf16<0><<<dim3(6, 64, 1), blk, 0, stream>>>(
        catb, 0, Hh * Dv, waggt, 0, Hh * Dv, bagg, 0, out, 0, Dv, Hh * Dv);
}

// Round 3
// 684.064 us; speedup vs baseline: 6.2139x; 1.0838x over previous
//
#include <hip/hip_runtime.h>

typedef long long i64;
typedef unsigned short u16;
typedef __attribute__((ext_vector_type(8))) short short8;
typedef __attribute__((ext_vector_type(4))) float f32x4;

#define Bv 8
#define Nv 1024
#define Dv 768
#define Hh 4
#define DKv 192
#define BND ((i64)Bv * Nv * Dv)      /* 6,291,456  */
#define HBND ((i64)Hh * BND)         /* 25,165,824 */

__device__ __forceinline__ u16 f2bf(float f) {
    unsigned u = __builtin_bit_cast(unsigned, f);
    u += 0x7fffu + ((u >> 16) & 1u);
    return (u16)(u >> 16);
}
__device__ __forceinline__ float bf2f(u16 h) {
    unsigned u = ((unsigned)h) << 16;
    return __builtin_bit_cast(float, u);
}

// async global->LDS, 16B per lane. LDS dest must be wave-uniform base.
__device__ __forceinline__ void gl_lds16(const u16* g, u16* l) {
    __builtin_amdgcn_global_load_lds(
        (const __attribute__((address_space(1))) void*)g,
        (__attribute__((address_space(3))) void*)l, 16, 0, 0);
}

// ---------------------------------------------------------------------------
// bf16 MFMA GEMM:  C[z] = epilogue( A[z] (MxK) @ Bt[z]^T (NxK) + bias[z] )
// 128x128 tile, BK=64, 256 threads (4 waves, 64x64 sub-tile each).
// SWAPPED mfma operand order: first operand = Bt rows (N side) so the C/D
// reg-dim runs along contiguous n -> vector epilogue (f32x4 / ushort4).
// XOR slot swizzle applied on BOTH source and read (rule 21); LDS dest linear.
// EPI: 0 = f32 store (+bias), 1 = bf16 store (+bias),
//      2 = X-update: X = bf16( bf2f(X) + relu(acc + bias) )  (u16*, RMW)
// CATK: A is X in (h,BN,768) layout; logical k = h*768 + d (cat view).
// koff: per-z k-origin (split-K); 0 otherwise.
// ---------------------------------------------------------------------------
template <int EPI, bool CATK>
__global__ __launch_bounds__(256) void gemm_bf16(
    const u16* __restrict__ A, i64 sA, int lda,
    const u16* __restrict__ Bt, i64 sBt, int ldbt,
    const float* __restrict__ bias, i64 sBias,
    void* __restrict__ Cv, i64 sC, int ldc, int K, int koff)
{
    __shared__ u16 Asb[128 * 64];
    __shared__ u16 Bsb[128 * 64];

    const int z = blockIdx.z;
    A  += (i64)z * sA;
    Bt += (i64)z * sBt;
    if (bias) bias += (i64)z * sBias;
    const int kb = z * koff;

    const int bm = blockIdx.y * 128, bn = blockIdx.x * 128;
    const int tid = threadIdx.x;
    const int w = tid >> 6, l = tid & 63;
    const int wr = w >> 1, wc = w & 1;
    const int kgrp = l >> 4, lr = l & 15;

    const u16* Ab = A + (i64)bm * lda;
    const u16* Bb = Bt + (i64)bn * ldbt;

    f32x4 acc[4][4];   // [i: n-frag (reg dim)][j: m-frag (lane dim)]
    #pragma unroll
    for (int i = 0; i < 4; ++i)
        #pragma unroll
        for (int j = 0; j < 4; ++j)
            acc[i][j] = (f32x4){0.f, 0.f, 0.f, 0.f};

    for (int k0i = 0; k0i < K; k0i += 64) {
        const int k0 = kb + k0i;
        if (k0i) __syncthreads();
        #pragma unroll
        for (int t = 0; t < 4; ++t) {
            const int idx = t * 256 + tid;
            const int r = idx >> 3, s = idx & 7;
            const int ss = s ^ (r & 7);
            const u16* src;
            if (CATK) {
                src = A + (i64)(k0 / Dv) * BND + (i64)(bm + r) * Dv + (k0 % Dv) + ss * 8;
            } else {
                src = Ab + (i64)r * lda + k0 + ss * 8;
            }
            gl_lds16(src, &Asb[(t * 256 + w * 64) * 8]);
        }
        #pragma unroll
        for (int t = 0; t < 4; ++t) {
            const int idx = t * 256 + tid;
            const int r = idx >> 3, s = idx & 7;
            const int ss = s ^ (r & 7);
            gl_lds16(Bb + (i64)r * ldbt + k0 + ss * 8, &Bsb[(t * 256 + w * 64) * 8]);
        }
        __syncthreads();

        #pragma unroll
        for (int ks = 0; ks < 2; ++ks) {
            const int slot = ks * 4 + kgrp;
            short8 a[4], b[4];
            #pragma unroll
            for (int i = 0; i < 4; ++i) {          // Bt rows (n side)
                const int r = wc * 64 + i * 16 + lr;
                a[i] = *(const short8*)&Bsb[r * 64 + ((slot ^ (r & 7)) << 3)];
            }
            #pragma unroll
            for (int j = 0; j < 4; ++j) {          // A rows (m side)
                const int r = wr * 64 + j * 16 + lr;
                b[j] = *(const short8*)&Asb[r * 64 + ((slot ^ (r & 7)) << 3)];
            }
            #pragma unroll
            for (int i = 0; i < 4; ++i)
                #pragma unroll
                for (int j = 0; j < 4; ++j)
                    acc[i][j] = __builtin_amdgcn_mfma_f32_16x16x32_bf16(
                        a[i], b[j], acc[i][j], 0, 0, 0);
        }
    }

    f32x4 bj[4];
    #pragma unroll
    for (int i = 0; i < 4; ++i) {
        const int nb = bn + wc * 64 + i * 16 + kgrp * 4;
        bj[i] = bias ? *(const f32x4*)&bias[nb] : (f32x4){0.f, 0.f, 0.f, 0.f};
    }

    #pragma unroll
    for (int j = 0; j < 4; ++j) {
        const int m = bm + wr * 64 + j * 16 + lr;
        #pragma unroll
        for (int i = 0; i < 4; ++i) {
            const int nb = bn + wc * 64 + i * 16 + kgrp * 4;
            const i64 off = (i64)z * sC + (i64)m * ldc + nb;
            f32x4 v = acc[i][j] + bj[i];
            if (EPI == 0) {
                *(f32x4*)&((float*)Cv)[off] = v;
            } else if (EPI == 1) {
                ushort4 o;
                o.x = f2bf(v[0]); o.y = f2bf(v[1]);
                o.z = f2bf(v[2]); o.w = f2bf(v[3]);
                *(ushort4*)&((u16*)Cv)[off] = o;
            } else {
                u16* xp = (u16*)Cv + off;
                ushort4 old = *(const ushort4*)xp;
                ushort4 o;
                o.x = f2bf(bf2f(old.x) + fmaxf(v[0], 0.f));
                o.y = f2bf(bf2f(old.y) + fmaxf(v[1], 0.f));
                o.z = f2bf(bf2f(old.z) + fmaxf(v[2], 0.f));
                o.w = f2bf(bf2f(old.w) + fmaxf(v[3], 0.f));
                *(ushort4*)xp = o;
            }
        }
    }
}

// ---------------------------------------------------------------------------
// Fused 3-edge masked scores (MFMA), swapped operands: first operand = K rows
// (m side) so each lane holds 4 contiguous m -> int4 adj loads, f32x4 stores.
// K staged in 64-chunks (LDS 16KB -> ~5 blocks/CU).
// ---------------------------------------------------------------------------
__global__ __launch_bounds__(256) void scores_mfma(
    const u16* __restrict__ qb, const u16* __restrict__ kb,
    const int* __restrict__ adj, float* __restrict__ ga)
{
    __shared__ u16 Qs[64 * 64];
    __shared__ u16 Ks[64 * 64];

    const int z = blockIdx.z;          // z = h*8 + b
    const int h = z >> 3, b = z & 7;
    const int m0 = blockIdx.x * 64, n0 = blockIdx.y * 64;
    const int tid = threadIdx.x;
    const int w = tid >> 6, l = tid & 63;
    const int wr = w >> 1, wc = w & 1;   // wr: n-half, wc: m-half
    const int kgrp = l >> 4, lr = l & 15;

    int4 adjv[2][2];
    #pragma unroll
    for (int i = 0; i < 2; ++i) {
        const int mb = m0 + wc * 32 + i * 16 + kgrp * 4;
        #pragma unroll
        for (int j = 0; j < 2; ++j) {
            const int n = n0 + wr * 32 + j * 16 + lr;
            adjv[i][j] = *(const int4*)&adj[((i64)b * Nv + n) * Nv + mb];
        }
    }

    f32x4 acc[3][2][2];
    #pragma unroll
    for (int e = 0; e < 3; ++e)
        #pragma unroll
        for (int i = 0; i < 2; ++i)
            #pragma unroll
            for (int j = 0; j < 2; ++j)
                acc[e][i][j] = (f32x4){0.f, 0.f, 0.f, 0.f};

    #pragma unroll
    for (int e = 0; e < 3; ++e) {
        const u16* qe = qb + (i64)e * BND + ((i64)b * Nv + n0) * Dv + h * DKv;
        const u16* ke = kb + (i64)e * BND + ((i64)b * Nv + m0) * Dv + h * DKv;
        #pragma unroll
        for (int c = 0; c < 3; ++c) {
            const int k0 = c * 64;
            __syncthreads();
            #pragma unroll
            for (int t = 0; t < 2; ++t) {
                const int idx = t * 256 + tid;
                const int r = idx >> 3, s = idx & 7;
                const int ss = s ^ (r & 7);
                gl_lds16(qe + (i64)r * Dv + k0 + ss * 8, &Qs[(t * 256 + w * 64) * 8]);
                gl_lds16(ke + (i64)r * Dv + k0 + ss * 8, &Ks[(t * 256 + w * 64) * 8]);
            }
            __syncthreads();
            #pragma unroll
            for (int ks = 0; ks < 2; ++ks) {
                const int slot = ks * 4 + kgrp;
                short8 a[2], bq[2];
                #pragma unroll
                for (int i = 0; i < 2; ++i) {          // K rows (m side)
                    const int r = wc * 32 + i * 16 + lr;
                    a[i] = *(const short8*)&Ks[r * 64 + ((slot ^ (r & 7)) << 3)];
                }
                #pragma unroll
                for (int j = 0; j < 2; ++j) {          // Q rows (n side)
                    const int r = wr * 32 + j * 16 + lr;
                    bq[j] = *(const short8*)&Qs[r * 64 + ((slot ^ (r & 7)) << 3)];
                }
                #pragma unroll
                for (int i = 0; i < 2; ++i)
                    #pragma unroll
                    for (int j = 0; j < 2; ++j)
                        acc[e][i][j] = __builtin_amdgcn_mfma_f32_16x16x32_bf16(
                            a[i], bq[j], acc[e][i][j], 0, 0, 0);
            }
        }
    }

    const float scale = 0.07216878364870323f;  // 1/sqrt(192)
    #pragma unroll
    for (int i = 0; i < 2; ++i) {
        const int mb = m0 + wc * 32 + i * 16 + kgrp * 4;
        #pragma unroll
        for (int j = 0; j < 2; ++j) {
            const int n = n0 + wr * 32 + j * 16 + lr;
            const int av[4] = {adjv[i][j].x, adjv[i][j].y, adjv[i][j].z, adjv[i][j].w};
            f32x4 o;
            #pragma unroll
            for (int rg = 0; rg < 4; ++rg) {
                float f = 0.f;
                if (av[rg] == 1) f = acc[0][i][j][rg];
                else if (av[rg] == 2) f = acc[1][i][j][rg];
                else if (av[rg] == 3) f = acc[2][i][j][rg];
                f *= scale;
                if (f == 0.f) f = -1e9f;
                o[rg] = f;
            }
            *(f32x4*)&ga[((i64)z * Nv + n) * Nv + mb] = o;
        }
    }
}

// in-place row softmax (1024 cols) + bf16 copy
__global__ __launch_bounds__(256) void softmax_k(float* __restrict__ ga,
                                                 u16* __restrict__ gab)
{
    const i64 row = blockIdx.x;
    float* p = ga + row * (i64)Nv;
    const int tid = threadIdx.x;
    const int wid = tid >> 6, lane = tid & 63;

    float4 v = *(float4*)&p[tid * 4];
    float m = fmaxf(fmaxf(v.x, v.y), fmaxf(v.z, v.w));
    #pragma unroll
    for (int o = 32; o >= 1; o >>= 1) m = fmaxf(m, __shfl_xor(m, o));

    __shared__ float red[4];
    if (lane == 0) red[wid] = m;
    __syncthreads();
    m = fmaxf(fmaxf(red[0], red[1]), fmaxf(red[2], red[3]));

    float e0 = expf(v.x - m), e1 = expf(v.y - m), e2 = expf(v.z - m), e3 = expf(v.w - m);
    float s = e0 + e1 + e2 + e3;
    #pragma unroll
    for (int o = 32; o >= 1; o >>= 1) s += __shfl_xor(s, o);
    __syncthreads();
    if (lane == 0) red[wid] = s;
    __syncthreads();
    s = red[0] + red[1] + red[2] + red[3];

    const float inv = 1.0f / s;
    float4 o;
    o.x = e0 * inv; o.y = e1 * inv; o.z = e2 * inv; o.w = e3 * inv;
    *(float4*)&p[tid * 4] = o;

    ushort4 ob;
    ob.x = f2bf(o.x); ob.y = f2bf(o.y); ob.z = f2bf(o.z); ob.w = f2bf(o.w);
    *(ushort4*)&gab[row * (i64)Nv + tid * 4] = ob;
}

// f32 -> bf16, 4 per thread
__global__ __launch_bounds__(256) void cvt_bf16_k(const float* __restrict__ in,
                                                  u16* __restrict__ out)
{
    const i64 i = (i64)blockIdx.x * 256 + threadIdx.x;
    float4 v = ((const float4*)in)[i];
    ushort4 o;
    o.x = f2bf(v.x); o.y = f2bf(v.y); o.z = f2bf(v.z); o.w = f2bf(v.w);
    ((ushort4*)out)[i] = o;
}

// batched transpose + bf16
__global__ __launch_bounds__(256) void transpose_bf16(
    const float* __restrict__ in, i64 sIn, u16* __restrict__ out, i64 sOut,
    int R, int C)
{
    __shared__ u16 t[32][33];
    const int z = blockIdx.z;
    in += (i64)z * sIn;
    out += (i64)z * sOut;
    const int c0 = blockIdx.x * 32, r0 = blockIdx.y * 32;
    const int tx = threadIdx.x & 31, ty = threadIdx.x >> 5;
    #pragma unroll
    for (int i = ty; i < 32; i += 8)
        t[i][tx] = f2bf(in[(i64)(r0 + i) * C + c0 + tx]);
    __syncthreads();
    #pragma unroll
    for (int i = ty; i < 32; i += 8)
        out[(i64)(c0 + i) * R + r0 + tx] = t[tx][i];
}

// X_bf16[h,b,n,d] = bf16(nodes[b,n,d])
__global__ __launch_bounds__(256) void xinit_k(const float* __restrict__ nodes,
                                               u16* __restrict__ Xb)
{
    const i64 i = (i64)blockIdx.x * 256 + threadIdx.x;  // over BND/4
    float4 v = ((const float4*)nodes)[i];
    ushort4 o;
    o.x = f2bf(v.x); o.y = f2bf(v.y); o.z = f2bf(v.z); o.w = f2bf(v.w);
    const i64 q4 = BND / 4;
    #pragma unroll
    for (int h = 0; h < Hh; ++h) ((ushort4*)Xb)[(i64)h * q4 + i] = o;
}

// out = p0 + p1 + bias (split-K reduce), float4 per thread
__global__ __launch_bounds__(256) void addbias_k(
    const float* __restrict__ p0, const float* __restrict__ p1,
    const float* __restrict__ bias, float* __restrict__ out)
{
    const i64 i4 = (i64)blockIdx.x * 256 + threadIdx.x;  // over BND/4
    const int nb = (int)((i4 * 4) % Dv);
    float4 a = ((const float4*)p0)[i4];
    float4 b = ((const float4*)p1)[i4];
    float4 bv = *(const float4*)&bias[nb];
    float4 o;
    o.x = a.x + b.x + bv.x; o.y = a.y + b.y + bv.y;
    o.z = a.z + b.z + bv.z; o.w = a.w + b.w + bv.w;
    ((float4*)out)[i4] = o;
}

// ---------------------------------------------------------------------------
extern "C" void kernel_launch(void* const* d_in, const int* in_sizes, int n_in,
                              void* d_out, int out_size, void* d_ws, size_t ws_size,
                              hipStream_t stream)
{
    const float* nodes = (const float*)d_in[0];
    const int*   adj   = (const int*)d_in[1];
    const float* Wq    = (const float*)d_in[2];
    const float* bq    = (const float*)d_in[3];
    const float* Wk    = (const float*)d_in[4];
    const float* bk    = (const float*)d_in[5];
    const float* gcnW  = (const float*)d_in[6];
    const float* gcnb  = (const float*)d_in[7];
    const float* Wagg  = (const float*)d_in[8];
    const float* bagg  = (const float*)d_in[9];

    float* out = (float*)d_out;             // (B,N,D) f32
    float* gaf = out + BND;                 // (H,B,N,N) f32

    const i64 W768 = (i64)768 * 768;
    u16* ws     = (u16*)d_ws;
    u16* qb     = ws;                       // 3*BND          (phase 1)
    u16* kb2    = ws + 3 * BND;             // 3*BND          (phase 1)
    u16* gab    = ws;                       // HBND bf16      (aliases q/k after scores)
    u16* nodesb = ws + 6 * BND;             // BND
    u16* gcnWt  = nodesb + BND;             // 2*W768
    u16* waggt  = gcnWt + 2 * W768;         // 768*3072
    u16* Xb     = waggt + (i64)768 * 3072;  // HBND
    u16* Htb    = Xb + HBND;                // HBND (H^T; dead after last Xupd)
    u16* wqt    = Htb;                      // 3*W768 (alias, dead before Ht)
    u16* wkt    = Htb + 3 * W768;           // 3*W768
    float* part = (float*)Htb;              // 2*BND f32 == HBND u16 bytes (alias)

    dim3 blk(256);

    cvt_bf16_k<<<dim3((unsigned)(BND / 4 / 256)), blk, 0, stream>>>(nodes, nodesb);

    transpose_bf16<<<dim3(24, 24, 3), blk, 0, stream>>>(Wq, W768, wqt, W768, 768, 768);
    transpose_bf16<<<dim3(24, 24, 3), blk, 0, stream>>>(Wk, W768, wkt, W768, 768, 768);
    transpose_bf16<<<dim3(24, 24, 2), blk, 0, stream>>>(gcnW, W768, gcnWt, W768, 768, 768);
    transpose_bf16<<<dim3(24, 96, 1), blk, 0, stream>>>(Wagg, 0, waggt, 0, 3072, 768);

    // q/k projections (bf16 out, +bias), batched over 3 edges
    gemm_bf16<1, false><<<dim3(6, 64, 3), blk, 0, stream>>>(
        nodesb, 0, Dv, wqt, W768, Dv, bq, Dv, qb, BND, Dv, Dv, 0);
    gemm_bf16<1, false><<<dim3(6, 64, 3), blk, 0, stream>>>(
        nodesb, 0, Dv, wkt, W768, Dv, bk, Dv, kb2, BND, Dv, Dv, 0);

    // fused masked scores -> ga f32 (d_out region)
    scores_mfma<<<dim3(16, 16, 32), blk, 0, stream>>>(qb, kb2, adj, gaf);

    // softmax in place + bf16 copy (gab aliases q/k, both dead now)
    softmax_k<<<dim3(Hh * Bv * Nv), blk, 0, stream>>>(gaf, gab);

    xinit_k<<<dim3((unsigned)(BND / 4 / 256)), blk, 0, stream>>>(nodes, Xb);

    for (int it = 0; it < 2; ++it) {
        // H^T = gcnW[it]^T @ X^T : A = gcnWt (768x768), Bt = Xb (32768x768)
        gemm_bf16<1, false><<<dim3(256, 6, 1), blk, 0, stream>>>(
            gcnWt + (i64)it * W768, 0, Dv, Xb, 0, Dv, nullptr, 0,
            Htb, 0, 32768, Dv, 0);
        // X += relu(ga @ H + b) : A = gab[z] (1024x1024), Bt = Ht cols z*1024..
        gemm_bf16<2, false><<<dim3(6, 8, 32), blk, 0, stream>>>(
            gab, (i64)Nv * Nv, Nv, Htb, 1024, 32768, gcnb + (i64)it * Dv, 0,
            Xb, (i64)Nv * Dv, Dv, Nv, 0);
    }

    // final: out = cat(X) @ W_agg + b_agg, split-K x2 into partials (over Htb)
    gemm_bf16<0, true><<<dim3(6, 64, 2), blk, 0, stream>>>(
        Xb, 0, Dv, waggt, 0, Hh * Dv, nullptr, 0,
        part, BND, Dv, (Hh * Dv) / 2, (Hh * Dv) / 2);

    addbias_k<<<dim3((unsigned)(BND / 4 / 256)), blk, 0, stream>>>(
        part, part + BND, bagg, out);
}

// Round 4
// 574.640 us; speedup vs baseline: 7.3972x; 1.1904x over previous
//
#include <hip/hip_runtime.h>

typedef long long i64;
typedef unsigned short u16;
typedef __attribute__((ext_vector_type(8))) short short8;
typedef __attribute__((ext_vector_type(4))) float f32x4;

#define Bv 8
#define Nv 1024
#define Dv 768
#define Hh 4
#define DKv 192
#define BND ((i64)Bv * Nv * Dv)      /* 6,291,456  */
#define HBND ((i64)Hh * BND)         /* 25,165,824 */

__device__ __forceinline__ u16 f2bf(float f) {
    unsigned u = __builtin_bit_cast(unsigned, f);
    u += 0x7fffu + ((u >> 16) & 1u);
    return (u16)(u >> 16);
}
__device__ __forceinline__ float bf2f(u16 h) {
    unsigned u = ((unsigned)h) << 16;
    return __builtin_bit_cast(float, u);
}

// async global->LDS, 16B per lane. LDS dest must be wave-uniform base.
__device__ __forceinline__ void gl_lds16(const u16* g, u16* l) {
    __builtin_amdgcn_global_load_lds(
        (const __attribute__((address_space(1))) void*)g,
        (__attribute__((address_space(3))) void*)l, 16, 0, 0);
}

// ---------------------------------------------------------------------------
// bf16 MFMA GEMM:  C[z] = epilogue( A[z] (MxK) @ Bt[z]^T (NxK) + bias[z] )
// 128x128 tile, BK=64, 256 threads (4 waves, 64x64 sub-tile each).
// Swapped mfma operand order (first operand = Bt rows) -> C/D reg dim runs
// along contiguous n -> vector epilogue. XOR slot swizzle both sides.
// 1D launch + XCD-chunked swizzle: L = (bid&7)*(grid/8) + (bid>>3);
// ORD 0: bn = L%NBN, bm = (L/NBN)%NBM, z = L/(NBN*NBM)   (bn fastest, z slow)
// ORD 1: bn = L%NBN, z  = (L/NBN)%NZ,  bm = L/(NBN*NZ)   (bm slowest)
// EPI: 0 = f32 store (+bias), 1 = bf16 store (+bias),
//      2 = X-update: X = bf16( bf2f(X) + relu(acc + bias) )  (u16*, RMW)
// CATK: A is X in (h,BN,768) layout; logical k = h*768 + d (cat view).
// bias2: if non-null, z >= NZ/2 uses bias2[z - NZ/2] (fused q/k dispatch).
// ---------------------------------------------------------------------------
template <int EPI, bool CATK, int ORD, int NBN, int NBM, int NZ>
__global__ __launch_bounds__(256) void gemm_bf16(
    const u16* __restrict__ A, i64 sA, int lda,
    const u16* __restrict__ Bt, i64 sBt, int ldbt,
    const float* __restrict__ bias, i64 sBias, const float* __restrict__ bias2,
    void* __restrict__ Cv, i64 sC, int ldc, int K, int koff)
{
    __shared__ u16 Asb[128 * 64];
    __shared__ u16 Bsb[128 * 64];

    const int L = (blockIdx.x & 7) * ((NBN * NBM * NZ) >> 3) + (blockIdx.x >> 3);
    int bn, bm, z;
    if (ORD == 0) {
        bn = L % NBN; const int t2 = L / NBN; bm = t2 % NBM; z = t2 / NBM;
    } else {
        bn = L % NBN; const int t2 = L / NBN; z = t2 % NZ; bm = t2 / NZ;
    }

    A  += (i64)z * sA;
    Bt += (i64)z * sBt;
    const float* bp = bias;
    int zb = z;
    if (bias2 != nullptr && z >= NZ / 2) { bp = bias2; zb = z - NZ / 2; }
    if (bp) bp += (i64)zb * sBias;
    const int kb = z * koff;

    const int bmp = bm * 128, bnp = bn * 128;
    const int tid = threadIdx.x;
    const int w = tid >> 6, l = tid & 63;
    const int wr = w >> 1, wc = w & 1;
    const int kgrp = l >> 4, lr = l & 15;

    const u16* Ab = A + (i64)bmp * lda;
    const u16* Bb = Bt + (i64)bnp * ldbt;

    f32x4 acc[4][4];   // [i: n-frag (reg dim)][j: m-frag (lane dim)]
    #pragma unroll
    for (int i = 0; i < 4; ++i)
        #pragma unroll
        for (int j = 0; j < 4; ++j)
            acc[i][j] = (f32x4){0.f, 0.f, 0.f, 0.f};

    for (int k0i = 0; k0i < K; k0i += 64) {
        const int k0 = kb + k0i;
        if (k0i) __syncthreads();
        #pragma unroll
        for (int t = 0; t < 4; ++t) {
            const int idx = t * 256 + tid;
            const int r = idx >> 3, s = idx & 7;
            const int ss = s ^ (r & 7);
            const u16* src;
            if (CATK) {
                src = A + (i64)(k0 / Dv) * BND + (i64)(bmp + r) * Dv + (k0 % Dv) + ss * 8;
            } else {
                src = Ab + (i64)r * lda + k0 + ss * 8;
            }
            gl_lds16(src, &Asb[(t * 256 + w * 64) * 8]);
        }
        #pragma unroll
        for (int t = 0; t < 4; ++t) {
            const int idx = t * 256 + tid;
            const int r = idx >> 3, s = idx & 7;
            const int ss = s ^ (r & 7);
            gl_lds16(Bb + (i64)r * ldbt + k0 + ss * 8, &Bsb[(t * 256 + w * 64) * 8]);
        }
        __syncthreads();

        #pragma unroll
        for (int ks = 0; ks < 2; ++ks) {
            const int slot = ks * 4 + kgrp;
            short8 a[4], b[4];
            #pragma unroll
            for (int i = 0; i < 4; ++i) {          // Bt rows (n side)
                const int r = wc * 64 + i * 16 + lr;
                a[i] = *(const short8*)&Bsb[r * 64 + ((slot ^ (r & 7)) << 3)];
            }
            #pragma unroll
            for (int j = 0; j < 4; ++j) {          // A rows (m side)
                const int r = wr * 64 + j * 16 + lr;
                b[j] = *(const short8*)&Asb[r * 64 + ((slot ^ (r & 7)) << 3)];
            }
            #pragma unroll
            for (int i = 0; i < 4; ++i)
                #pragma unroll
                for (int j = 0; j < 4; ++j)
                    acc[i][j] = __builtin_amdgcn_mfma_f32_16x16x32_bf16(
                        a[i], b[j], acc[i][j], 0, 0, 0);
        }
    }

    f32x4 bj[4];
    #pragma unroll
    for (int i = 0; i < 4; ++i) {
        const int nb = bnp + wc * 64 + i * 16 + kgrp * 4;
        bj[i] = bp ? *(const f32x4*)&bp[nb] : (f32x4){0.f, 0.f, 0.f, 0.f};
    }

    #pragma unroll
    for (int j = 0; j < 4; ++j) {
        const int m = bmp + wr * 64 + j * 16 + lr;
        #pragma unroll
        for (int i = 0; i < 4; ++i) {
            const int nb = bnp + wc * 64 + i * 16 + kgrp * 4;
            const i64 off = (i64)z * sC + (i64)m * ldc + nb;
            f32x4 v = acc[i][j] + bj[i];
            if (EPI == 0) {
                *(f32x4*)&((float*)Cv)[off] = v;
            } else if (EPI == 1) {
                ushort4 o;
                o.x = f2bf(v[0]); o.y = f2bf(v[1]);
                o.z = f2bf(v[2]); o.w = f2bf(v[3]);
                *(ushort4*)&((u16*)Cv)[off] = o;
            } else {
                u16* xp = (u16*)Cv + off;
                ushort4 old = *(const ushort4*)xp;
                ushort4 o;
                o.x = f2bf(bf2f(old.x) + fmaxf(v[0], 0.f));
                o.y = f2bf(bf2f(old.y) + fmaxf(v[1], 0.f));
                o.z = f2bf(bf2f(old.z) + fmaxf(v[2], 0.f));
                o.w = f2bf(bf2f(old.w) + fmaxf(v[3], 0.f));
                *(ushort4*)xp = o;
            }
        }
    }
}

// ---------------------------------------------------------------------------
// Fused 3-edge masked scores (MFMA), 2-phase double-buffered staging with
// counted vmcnt (never 0 mid-loop) + raw barriers. Writes S as bf16 to sb.
// 1D launch 8192: b = bid&7 (b-per-XCD), then h-fastest, mt, nt (adj reuse).
// ---------------------------------------------------------------------------
__global__ __launch_bounds__(256) void scores_mfma(
    const u16* __restrict__ qb, const u16* __restrict__ kb,
    const int* __restrict__ adj, u16* __restrict__ sb)
{
    __shared__ u16 Qs[2][64 * 64];
    __shared__ u16 Ks[2][64 * 64];

    const int bid = blockIdx.x;
    const int b = bid & 7;
    const int t2 = bid >> 3;          // [0,1024)
    const int h = t2 & 3;
    const int mt = (t2 >> 2) & 15;
    const int nt = t2 >> 6;
    const int m0 = mt * 64, n0 = nt * 64;
    const int zga = h * 8 + b;

    const int tid = threadIdx.x;
    const int w = tid >> 6, l = tid & 63;
    const int wr = w >> 1, wc = w & 1;   // wr: n-half, wc: m-half
    const int kgrp = l >> 4, lr = l & 15;

    const i64 qoff = ((i64)b * Nv + n0) * Dv + h * DKv;
    const i64 koff = ((i64)b * Nv + m0) * Dv + h * DKv;

#define STAGE_SC(ci_, buf_) { \
    const int e_ = (ci_) / 3, k0_ = ((ci_) % 3) * 64; \
    const u16* qe_ = qb + (i64)e_ * BND + qoff; \
    const u16* ke_ = kb + (i64)e_ * BND + koff; \
    _Pragma("unroll") \
    for (int t = 0; t < 2; ++t) { \
        const int idx2 = t * 256 + tid; \
        const int r = idx2 >> 3, s = idx2 & 7; \
        const int ss = s ^ (r & 7); \
        gl_lds16(qe_ + (i64)r * Dv + k0_ + ss * 8, &Qs[buf_][(t * 256 + w * 64) * 8]); \
        gl_lds16(ke_ + (i64)r * Dv + k0_ + ss * 8, &Ks[buf_][(t * 256 + w * 64) * 8]); \
    } }

    int4 adjv[2][2];
    #pragma unroll
    for (int i = 0; i < 2; ++i) {
        const int mb = m0 + wc * 32 + i * 16 + kgrp * 4;
        #pragma unroll
        for (int j = 0; j < 2; ++j) {
            const int n = n0 + wr * 32 + j * 16 + lr;
            adjv[i][j] = *(const int4*)&adj[((i64)b * Nv + n) * Nv + mb];
        }
    }

    f32x4 acc[3][2][2];
    #pragma unroll
    for (int e = 0; e < 3; ++e)
        #pragma unroll
        for (int i = 0; i < 2; ++i)
            #pragma unroll
            for (int j = 0; j < 2; ++j)
                acc[e][i][j] = (f32x4){0.f, 0.f, 0.f, 0.f};

    STAGE_SC(0, 0)

    #pragma unroll
    for (int ci = 0; ci < 9; ++ci) {
        const int cur = ci & 1;
        if (ci < 8) {
            if (cur) { STAGE_SC(ci + 1, 0) } else { STAGE_SC(ci + 1, 1) }
            asm volatile("s_waitcnt vmcnt(4)" ::: "memory");
        } else {
            asm volatile("s_waitcnt vmcnt(0)" ::: "memory");
        }
        __builtin_amdgcn_s_barrier();
        asm volatile("" ::: "memory");

        const int e = ci / 3;
        #pragma unroll
        for (int ks = 0; ks < 2; ++ks) {
            const int slot = ks * 4 + kgrp;
            short8 a[2], bq2[2];
            #pragma unroll
            for (int i = 0; i < 2; ++i) {          // K rows (m side)
                const int r = wc * 32 + i * 16 + lr;
                a[i] = *(const short8*)&Ks[cur][r * 64 + ((slot ^ (r & 7)) << 3)];
            }
            #pragma unroll
            for (int j = 0; j < 2; ++j) {          // Q rows (n side)
                const int r = wr * 32 + j * 16 + lr;
                bq2[j] = *(const short8*)&Qs[cur][r * 64 + ((slot ^ (r & 7)) << 3)];
            }
            #pragma unroll
            for (int i = 0; i < 2; ++i)
                #pragma unroll
                for (int j = 0; j < 2; ++j)
                    acc[e][i][j] = __builtin_amdgcn_mfma_f32_16x16x32_bf16(
                        a[i], bq2[j], acc[e][i][j], 0, 0, 0);
        }

        asm volatile("s_waitcnt lgkmcnt(0)" ::: "memory");
        __builtin_amdgcn_s_barrier();
    }
#undef STAGE_SC

    const float scale = 0.07216878364870323f;  // 1/sqrt(192)
    #pragma unroll
    for (int i = 0; i < 2; ++i) {
        const int mb = m0 + wc * 32 + i * 16 + kgrp * 4;
        #pragma unroll
        for (int j = 0; j < 2; ++j) {
            const int n = n0 + wr * 32 + j * 16 + lr;
            const int av[4] = {adjv[i][j].x, adjv[i][j].y, adjv[i][j].z, adjv[i][j].w};
            ushort4 o;
            #pragma unroll
            for (int rg = 0; rg < 4; ++rg) {
                float f = 0.f;
                if (av[rg] == 1) f = acc[0][i][j][rg];
                else if (av[rg] == 2) f = acc[1][i][j][rg];
                else if (av[rg] == 3) f = acc[2][i][j][rg];
                f *= scale;
                if (f == 0.f) f = -1e9f;
                ((u16*)&o)[rg] = f2bf(f);
            }
            *(ushort4*)&sb[((i64)zga * Nv + n) * Nv + mb] = o;
        }
    }
}

// row softmax over 1024 cols: read S bf16, write ga f32 (output) + P bf16
__global__ __launch_bounds__(256) void softmax_k(const u16* __restrict__ sb,
                                                 float* __restrict__ ga,
                                                 u16* __restrict__ gab)
{
    const i64 row = blockIdx.x;
    const int tid = threadIdx.x;
    const int wid = tid >> 6, lane = tid & 63;

    ushort4 sv = *(const ushort4*)&sb[row * (i64)Nv + tid * 4];
    float4 v;
    v.x = bf2f(sv.x); v.y = bf2f(sv.y); v.z = bf2f(sv.z); v.w = bf2f(sv.w);

    float m = fmaxf(fmaxf(v.x, v.y), fmaxf(v.z, v.w));
    #pragma unroll
    for (int o = 32; o >= 1; o >>= 1) m = fmaxf(m, __shfl_xor(m, o));

    __shared__ float red[4];
    if (lane == 0) red[wid] = m;
    __syncthreads();
    m = fmaxf(fmaxf(red[0], red[1]), fmaxf(red[2], red[3]));

    float e0 = expf(v.x - m), e1 = expf(v.y - m), e2 = expf(v.z - m), e3 = expf(v.w - m);
    float s = e0 + e1 + e2 + e3;
    #pragma unroll
    for (int o = 32; o >= 1; o >>= 1) s += __shfl_xor(s, o);
    __syncthreads();
    if (lane == 0) red[wid] = s;
    __syncthreads();
    s = red[0] + red[1] + red[2] + red[3];

    const float inv = 1.0f / s;
    float4 o;
    o.x = e0 * inv; o.y = e1 * inv; o.z = e2 * inv; o.w = e3 * inv;
    *(float4*)&ga[row * (i64)Nv + tid * 4] = o;

    ushort4 ob;
    ob.x = f2bf(o.x); ob.y = f2bf(o.y); ob.z = f2bf(o.z); ob.w = f2bf(o.w);
    *(ushort4*)&gab[row * (i64)Nv + tid * 4] = ob;
}

// nodes f32 -> nodesb bf16 + X broadcast x4 (one read, five writes)
__global__ __launch_bounds__(256) void prep_k(const float* __restrict__ nodes,
                                              u16* __restrict__ nodesb,
                                              u16* __restrict__ Xb)
{
    const i64 i = (i64)blockIdx.x * 256 + threadIdx.x;  // over BND/4
    float4 v = ((const float4*)nodes)[i];
    ushort4 o;
    o.x = f2bf(v.x); o.y = f2bf(v.y); o.z = f2bf(v.z); o.w = f2bf(v.w);
    ((ushort4*)nodesb)[i] = o;
    const i64 q4 = BND / 4;
    #pragma unroll
    for (int h = 0; h < Hh; ++h) ((ushort4*)Xb)[(i64)h * q4 + i] = o;
}

// all weight transposes in one dispatch. z<3: Wq[e]; 3..5: Wk[e]; 6,7: gcnW;
// 8..11: Wagg 768-row slice. All 768x768 transposes.
__global__ __launch_bounds__(256) void trans_all(
    const float* __restrict__ Wq, const float* __restrict__ Wk,
    const float* __restrict__ gcnW, const float* __restrict__ Wagg,
    u16* __restrict__ wqkt, u16* __restrict__ gcnWt, u16* __restrict__ waggt)
{
    const int z = blockIdx.z;
    const i64 W768 = (i64)768 * 768;
    const float* src;
    u16* dst;
    int ldo;
    if (z < 3)      { src = Wq + z * W768;        dst = wqkt + z * W768;          ldo = 768; }
    else if (z < 6) { src = Wk + (z - 3) * W768;  dst = wqkt + (i64)z * W768;     ldo = 768; }
    else if (z < 8) { src = gcnW + (z - 6) * W768; dst = gcnWt + (i64)(z - 6) * W768; ldo = 768; }
    else            { src = Wagg + (i64)(z - 8) * W768; dst = waggt + (i64)(z - 8) * 768; ldo = 3072; }

    __shared__ u16 t[32][33];
    const int c0 = blockIdx.x * 32, r0 = blockIdx.y * 32;
    const int tx = threadIdx.x & 31, ty = threadIdx.x >> 5;
    #pragma unroll
    for (int i = ty; i < 32; i += 8)
        t[i][tx] = f2bf(src[(i64)(r0 + i) * 768 + c0 + tx]);
    __syncthreads();
    #pragma unroll
    for (int i = ty; i < 32; i += 8)
        dst[(i64)(c0 + i) * ldo + r0 + tx] = t[tx][i];
}

// out = p0 + p1 + bias (split-K reduce), float4 per thread
__global__ __launch_bounds__(256) void addbias_k(
    const float* __restrict__ p0, const float* __restrict__ p1,
    const float* __restrict__ bias, float* __restrict__ out)
{
    const i64 i4 = (i64)blockIdx.x * 256 + threadIdx.x;  // over BND/4
    const int nb = (int)((i4 * 4) % Dv);
    float4 a = ((const float4*)p0)[i4];
    float4 b = ((const float4*)p1)[i4];
    float4 bv = *(const float4*)&bias[nb];
    float4 o;
    o.x = a.x + b.x + bv.x; o.y = a.y + b.y + bv.y;
    o.z = a.z + b.z + bv.z; o.w = a.w + b.w + bv.w;
    ((float4*)out)[i4] = o;
}

// ---------------------------------------------------------------------------
extern "C" void kernel_launch(void* const* d_in, const int* in_sizes, int n_in,
                              void* d_out, int out_size, void* d_ws, size_t ws_size,
                              hipStream_t stream)
{
    const float* nodes = (const float*)d_in[0];
    const int*   adj   = (const int*)d_in[1];
    const float* Wq    = (const float*)d_in[2];
    const float* bq    = (const float*)d_in[3];
    const float* Wk    = (const float*)d_in[4];
    const float* bk    = (const float*)d_in[5];
    const float* gcnW  = (const float*)d_in[6];
    const float* gcnb  = (const float*)d_in[7];
    const float* Wagg  = (const float*)d_in[8];
    const float* bagg  = (const float*)d_in[9];

    float* out = (float*)d_out;             // (B,N,D) f32
    float* gaf = out + BND;                 // (H,B,N,N) f32

    const i64 W768 = (i64)768 * 768;
    u16* ws     = (u16*)d_ws;
    u16* qb     = ws;                       // 3*BND           (phase 1)
    u16* kb2    = ws + 3 * BND;             // 3*BND           (phase 1)
    u16* gab    = ws;                       // HBND bf16       (alias after scores)
    u16* nodesb = ws + 6 * BND;             // BND
    u16* gcnWt  = nodesb + BND;             // 2*W768
    u16* waggt  = gcnWt + 2 * W768;         // 4*W768
    u16* Xb     = waggt + 4 * W768;         // HBND
    u16* Htb    = Xb + HBND;                // HBND region, time-shared:
    u16* wqkt   = Htb;                      //   6*W768 (dead after q/k proj)
    u16* sbuf   = Htb;                      //   HBND (S bf16; dead after softmax)
    float* part = (float*)Htb;              //   2*BND f32 (final split-K)

    dim3 blk(256);

    prep_k<<<dim3((unsigned)(BND / 4 / 256)), blk, 0, stream>>>(nodes, nodesb, Xb);
    trans_all<<<dim3(24, 24, 12), blk, 0, stream>>>(Wq, Wk, gcnW, Wagg, wqkt, gcnWt, waggt);

    // fused q/k projections: z 0..2 -> q (bias bq), z 3..5 -> k (bias bk)
    gemm_bf16<1, false, 1, 6, 64, 6><<<dim3(2304), blk, 0, stream>>>(
        nodesb, 0, Dv, wqkt, W768, Dv, bq, Dv, bk, qb, BND, Dv, Dv, 0);

    // fused masked scores -> S bf16 scratch
    scores_mfma<<<dim3(8192), blk, 0, stream>>>(qb, kb2, adj, sbuf);

    // softmax: ga f32 (output) + P bf16 (gab aliases q/k, both dead now)
    softmax_k<<<dim3(Hh * Bv * Nv), blk, 0, stream>>>(sbuf, gaf, gab);

    for (int it = 0; it < 2; ++it) {
        // H^T = gcnW[it]^T @ X^T : A = gcnWt (768x768), Bt = Xb (32768x768)
        gemm_bf16<1, false, 0, 256, 6, 1><<<dim3(1536), blk, 0, stream>>>(
            gcnWt + (i64)it * W768, 0, Dv, Xb, 0, Dv, nullptr, 0, nullptr,
            Htb, 0, 32768, Dv, 0);
        // X += relu(ga @ H + b) : A = gab[z], Bt = Ht cols z*1024.. (z-per-XCD)
        gemm_bf16<2, false, 0, 6, 8, 32><<<dim3(1536), blk, 0, stream>>>(
            gab, (i64)Nv * Nv, Nv, Htb, 1024, 32768, gcnb + (i64)it * Dv, 0, nullptr,
            Xb, (i64)Nv * Dv, Dv, Nv, 0);
    }

    // final: out = cat(X) @ W_agg + b_agg, split-K x2 into f32 partials
    gemm_bf16<0, true, 0, 6, 64, 2><<<dim3(768), blk, 0, stream>>>(
        Xb, 0, Dv, waggt, 0, Hh * Dv, nullptr, 0, nullptr,
        part, BND, Dv, (Hh * Dv) / 2, (Hh * Dv) / 2);

    addbias_k<<<dim3((unsigned)(BND / 4 / 256)), blk, 0, stream>>>(
        part, part + BND, bagg, out);
}

// Round 5
// 550.896 us; speedup vs baseline: 7.7160x; 1.0431x over previous
//
#include <hip/hip_runtime.h>

typedef long long i64;
typedef unsigned short u16;
typedef __attribute__((ext_vector_type(8))) short short8;
typedef __attribute__((ext_vector_type(4))) float f32x4;

#define Bv 8
#define Nv 1024
#define Dv 768
#define Hh 4
#define DKv 192
#define BND ((i64)Bv * Nv * Dv)      /* 6,291,456  */
#define HBND ((i64)Hh * BND)         /* 25,165,824 */

__device__ __forceinline__ u16 f2bf(float f) {
    unsigned u = __builtin_bit_cast(unsigned, f);
    u += 0x7fffu + ((u >> 16) & 1u);
    return (u16)(u >> 16);
}
__device__ __forceinline__ float bf2f(u16 h) {
    unsigned u = ((unsigned)h) << 16;
    return __builtin_bit_cast(float, u);
}

// async global->LDS, 16B per lane. LDS dest must be wave-uniform base.
__device__ __forceinline__ void gl_lds16(const u16* g, u16* l) {
    __builtin_amdgcn_global_load_lds(
        (const __attribute__((address_space(1))) void*)g,
        (__attribute__((address_space(3))) void*)l, 16, 0, 0);
}

// ---------------------------------------------------------------------------
// bf16 MFMA GEMM:  C[z] = epilogue( A[z] (MxK) @ Bt[z]^T (NxK) + bias[z] )
// 128x128 tile, BK=64, 256 threads (4 waves, 64x64 sub-tile each).
// Swapped mfma operand order (first operand = Bt rows) -> C/D reg dim runs
// along contiguous n -> vector epilogue. XOR slot swizzle both sides.
// 1D launch + XCD-chunked swizzle: L = (bid&7)*(grid/8) + (bid>>3);
// ORD 0: bn = L%NBN, bm = (L/NBN)%NBM, z = L/(NBN*NBM)   (bn fastest, z slow)
// ORD 1: bn = L%NBN, z  = (L/NBN)%NZ,  bm = L/(NBN*NZ)   (bm slowest)
// EPI: 0 = f32 store (+bias), 1 = bf16 store (+bias),
//      2 = X-update: X = bf16( bf2f(X) + relu(acc + bias) )  (u16*, RMW)
// CATK: A is X in (h,BN,768) layout; logical k = h*768 + d (cat view).
// bias2: if non-null, z >= NZ/2 uses bias2[z - NZ/2] (fused q/k dispatch).
// zmaskBt: Bt batch offset uses (z & zmaskBt) (iter-0 shared-H indexing).
// ---------------------------------------------------------------------------
template <int EPI, bool CATK, int ORD, int NBN, int NBM, int NZ>
__global__ __launch_bounds__(256) void gemm_bf16(
    const u16* __restrict__ A, i64 sA, int lda,
    const u16* __restrict__ Bt, i64 sBt, int ldbt, int zmaskBt,
    const float* __restrict__ bias, i64 sBias, const float* __restrict__ bias2,
    void* __restrict__ Cv, i64 sC, int ldc, int K, int koff)
{
    __shared__ u16 Asb[128 * 64];
    __shared__ u16 Bsb[128 * 64];

    const int L = (blockIdx.x & 7) * ((NBN * NBM * NZ) >> 3) + (blockIdx.x >> 3);
    int bn, bm, z;
    if (ORD == 0) {
        bn = L % NBN; const int t2 = L / NBN; bm = t2 % NBM; z = t2 / NBM;
    } else {
        bn = L % NBN; const int t2 = L / NBN; z = t2 % NZ; bm = t2 / NZ;
    }

    A  += (i64)z * sA;
    Bt += (i64)(z & zmaskBt) * sBt;
    const float* bp = bias;
    int zb = z;
    if (bias2 != nullptr && z >= NZ / 2) { bp = bias2; zb = z - NZ / 2; }
    if (bp) bp += (i64)zb * sBias;
    const int kb = z * koff;

    const int bmp = bm * 128, bnp = bn * 128;
    const int tid = threadIdx.x;
    const int w = tid >> 6, l = tid & 63;
    const int wr = w >> 1, wc = w & 1;
    const int kgrp = l >> 4, lr = l & 15;

    const u16* Ab = A + (i64)bmp * lda;
    const u16* Bb = Bt + (i64)bnp * ldbt;

    f32x4 acc[4][4];   // [i: n-frag (reg dim)][j: m-frag (lane dim)]
    #pragma unroll
    for (int i = 0; i < 4; ++i)
        #pragma unroll
        for (int j = 0; j < 4; ++j)
            acc[i][j] = (f32x4){0.f, 0.f, 0.f, 0.f};

    for (int k0i = 0; k0i < K; k0i += 64) {
        const int k0 = kb + k0i;
        if (k0i) __syncthreads();
        #pragma unroll
        for (int t = 0; t < 4; ++t) {
            const int idx = t * 256 + tid;
            const int r = idx >> 3, s = idx & 7;
            const int ss = s ^ (r & 7);
            const u16* src;
            if (CATK) {
                src = A + (i64)(k0 / Dv) * BND + (i64)(bmp + r) * Dv + (k0 % Dv) + ss * 8;
            } else {
                src = Ab + (i64)r * lda + k0 + ss * 8;
            }
            gl_lds16(src, &Asb[(t * 256 + w * 64) * 8]);
        }
        #pragma unroll
        for (int t = 0; t < 4; ++t) {
            const int idx = t * 256 + tid;
            const int r = idx >> 3, s = idx & 7;
            const int ss = s ^ (r & 7);
            gl_lds16(Bb + (i64)r * ldbt + k0 + ss * 8, &Bsb[(t * 256 + w * 64) * 8]);
        }
        __syncthreads();

        #pragma unroll
        for (int ks = 0; ks < 2; ++ks) {
            const int slot = ks * 4 + kgrp;
            short8 a[4], b[4];
            #pragma unroll
            for (int i = 0; i < 4; ++i) {          // Bt rows (n side)
                const int r = wc * 64 + i * 16 + lr;
                a[i] = *(const short8*)&Bsb[r * 64 + ((slot ^ (r & 7)) << 3)];
            }
            #pragma unroll
            for (int j = 0; j < 4; ++j) {          // A rows (m side)
                const int r = wr * 64 + j * 16 + lr;
                b[j] = *(const short8*)&Asb[r * 64 + ((slot ^ (r & 7)) << 3)];
            }
            #pragma unroll
            for (int i = 0; i < 4; ++i)
                #pragma unroll
                for (int j = 0; j < 4; ++j)
                    acc[i][j] = __builtin_amdgcn_mfma_f32_16x16x32_bf16(
                        a[i], b[j], acc[i][j], 0, 0, 0);
        }
    }

    f32x4 bj[4];
    #pragma unroll
    for (int i = 0; i < 4; ++i) {
        const int nb = bnp + wc * 64 + i * 16 + kgrp * 4;
        bj[i] = bp ? *(const f32x4*)&bp[nb] : (f32x4){0.f, 0.f, 0.f, 0.f};
    }

    #pragma unroll
    for (int j = 0; j < 4; ++j) {
        const int m = bmp + wr * 64 + j * 16 + lr;
        #pragma unroll
        for (int i = 0; i < 4; ++i) {
            const int nb = bnp + wc * 64 + i * 16 + kgrp * 4;
            const i64 off = (i64)z * sC + (i64)m * ldc + nb;
            f32x4 v = acc[i][j] + bj[i];
            if (EPI == 0) {
                *(f32x4*)&((float*)Cv)[off] = v;
            } else if (EPI == 1) {
                ushort4 o;
                o.x = f2bf(v[0]); o.y = f2bf(v[1]);
                o.z = f2bf(v[2]); o.w = f2bf(v[3]);
                *(ushort4*)&((u16*)Cv)[off] = o;
            } else {
                u16* xp = (u16*)Cv + off;
                ushort4 old = *(const ushort4*)xp;
                ushort4 o;
                o.x = f2bf(bf2f(old.x) + fmaxf(v[0], 0.f));
                o.y = f2bf(bf2f(old.y) + fmaxf(v[1], 0.f));
                o.z = f2bf(bf2f(old.z) + fmaxf(v[2], 0.f));
                o.w = f2bf(bf2f(old.w) + fmaxf(v[3], 0.f));
                *(ushort4*)xp = o;
            }
        }
    }
}

// ---------------------------------------------------------------------------
// Fused 3-edge masked scores (MFMA), 128n x 64m tile, 2-phase double-buffered
// staging with counted vmcnt (never 0 mid-loop) + raw barriers. S -> bf16.
// 1D launch 4096: b = bid&7 (b-per-XCD), then h fastest, mt, nt (adj reuse).
// 16 MFMA per phase per wave (2x round-4 density), 9 phases, 3 blocks/CU.
// ---------------------------------------------------------------------------
__global__ __launch_bounds__(256, 3) void scores_mfma(
    const u16* __restrict__ qb, const u16* __restrict__ kb,
    const int* __restrict__ adj, u16* __restrict__ sb)
{
    __shared__ u16 Qs[2][128 * 64];   // 32 KB
    __shared__ u16 Ks[2][64 * 64];    // 16 KB

    const int bid = blockIdx.x;
    const int b = bid & 7;
    const int t2 = bid >> 3;          // [0,512)
    const int h = t2 & 3;
    const int mt = (t2 >> 2) & 15;
    const int nt = t2 >> 6;           // [0,8)
    const int m0 = mt * 64, n0 = nt * 128;
    const int zga = h * 8 + b;

    const int tid = threadIdx.x;
    const int w = tid >> 6, l = tid & 63;
    const int wn = w >> 1, wm = w & 1;   // wn: n-half (64 rows), wm: m-half (32)
    const int kgrp = l >> 4, lr = l & 15;

    const i64 qoff = ((i64)b * Nv + n0) * Dv + h * DKv;
    const i64 koff = ((i64)b * Nv + m0) * Dv + h * DKv;

#define STAGE_SC(ci_, buf_) { \
    const int e_ = (ci_) / 3, k0_ = ((ci_) % 3) * 64; \
    const u16* qe_ = qb + (i64)e_ * BND + qoff; \
    const u16* ke_ = kb + (i64)e_ * BND + koff; \
    _Pragma("unroll") \
    for (int t = 0; t < 4; ++t) { \
        const int idx2 = t * 256 + tid; \
        const int r = idx2 >> 3, s = idx2 & 7; \
        const int ss = s ^ (r & 7); \
        gl_lds16(qe_ + (i64)r * Dv + k0_ + ss * 8, &Qs[buf_][(t * 256 + w * 64) * 8]); \
    } \
    _Pragma("unroll") \
    for (int t = 0; t < 2; ++t) { \
        const int idx2 = t * 256 + tid; \
        const int r = idx2 >> 3, s = idx2 & 7; \
        const int ss = s ^ (r & 7); \
        gl_lds16(ke_ + (i64)r * Dv + k0_ + ss * 8, &Ks[buf_][(t * 256 + w * 64) * 8]); \
    } }

    f32x4 acc[3][2][4];   // [edge][m-frag (reg dim)][n-frag (lane dim)]
    #pragma unroll
    for (int e = 0; e < 3; ++e)
        #pragma unroll
        for (int i = 0; i < 2; ++i)
            #pragma unroll
            for (int j = 0; j < 4; ++j)
                acc[e][i][j] = (f32x4){0.f, 0.f, 0.f, 0.f};

    STAGE_SC(0, 0)

    #pragma unroll
    for (int ci = 0; ci < 9; ++ci) {
        const int cur = ci & 1;
        if (ci < 8) {
            if (cur) { STAGE_SC(ci + 1, 0) } else { STAGE_SC(ci + 1, 1) }
            asm volatile("s_waitcnt vmcnt(6)" ::: "memory");
        } else {
            asm volatile("s_waitcnt vmcnt(0)" ::: "memory");
        }
        __builtin_amdgcn_s_barrier();
        asm volatile("" ::: "memory");

        const int e = ci / 3;
        #pragma unroll
        for (int ks = 0; ks < 2; ++ks) {
            const int slot = ks * 4 + kgrp;
            short8 a[2], bq2[4];
            #pragma unroll
            for (int i = 0; i < 2; ++i) {          // K rows (m side, reg dim)
                const int r = wm * 32 + i * 16 + lr;
                a[i] = *(const short8*)&Ks[cur][r * 64 + ((slot ^ (r & 7)) << 3)];
            }
            #pragma unroll
            for (int j = 0; j < 4; ++j) {          // Q rows (n side, lane dim)
                const int r = wn * 64 + j * 16 + lr;
                bq2[j] = *(const short8*)&Qs[cur][r * 64 + ((slot ^ (r & 7)) << 3)];
            }
            #pragma unroll
            for (int i = 0; i < 2; ++i)
                #pragma unroll
                for (int j = 0; j < 4; ++j)
                    acc[e][i][j] = __builtin_amdgcn_mfma_f32_16x16x32_bf16(
                        a[i], bq2[j], acc[e][i][j], 0, 0, 0);
        }

        asm volatile("s_waitcnt lgkmcnt(0)" ::: "memory");
        __builtin_amdgcn_s_barrier();
    }
#undef STAGE_SC

    const float scale = 0.07216878364870323f;  // 1/sqrt(192)
    #pragma unroll
    for (int i = 0; i < 2; ++i) {
        const int mb = m0 + wm * 32 + i * 16 + kgrp * 4;
        #pragma unroll
        for (int j = 0; j < 4; ++j) {
            const int n = n0 + wn * 64 + j * 16 + lr;
            const int4 adjv = *(const int4*)&adj[((i64)b * Nv + n) * Nv + mb];
            const int av[4] = {adjv.x, adjv.y, adjv.z, adjv.w};
            ushort4 o;
            #pragma unroll
            for (int rg = 0; rg < 4; ++rg) {
                float f = 0.f;
                if (av[rg] == 1) f = acc[0][i][j][rg];
                else if (av[rg] == 2) f = acc[1][i][j][rg];
                else if (av[rg] == 3) f = acc[2][i][j][rg];
                f *= scale;
                if (f == 0.f) f = -1e9f;
                ((u16*)&o)[rg] = f2bf(f);
            }
            *(ushort4*)&sb[((i64)zga * Nv + n) * Nv + mb] = o;
        }
    }
}

// row softmax over 1024 cols: read S bf16, write ga f32 (output) + P bf16
__global__ __launch_bounds__(256) void softmax_k(const u16* __restrict__ sb,
                                                 float* __restrict__ ga,
                                                 u16* __restrict__ gab)
{
    const i64 row = blockIdx.x;
    const int tid = threadIdx.x;
    const int wid = tid >> 6, lane = tid & 63;

    ushort4 sv = *(const ushort4*)&sb[row * (i64)Nv + tid * 4];
    float4 v;
    v.x = bf2f(sv.x); v.y = bf2f(sv.y); v.z = bf2f(sv.z); v.w = bf2f(sv.w);

    float m = fmaxf(fmaxf(v.x, v.y), fmaxf(v.z, v.w));
    #pragma unroll
    for (int o = 32; o >= 1; o >>= 1) m = fmaxf(m, __shfl_xor(m, o));

    __shared__ float red[4];
    if (lane == 0) red[wid] = m;
    __syncthreads();
    m = fmaxf(fmaxf(red[0], red[1]), fmaxf(red[2], red[3]));

    float e0 = expf(v.x - m), e1 = expf(v.y - m), e2 = expf(v.z - m), e3 = expf(v.w - m);
    float s = e0 + e1 + e2 + e3;
    #pragma unroll
    for (int o = 32; o >= 1; o >>= 1) s += __shfl_xor(s, o);
    __syncthreads();
    if (lane == 0) red[wid] = s;
    __syncthreads();
    s = red[0] + red[1] + red[2] + red[3];

    const float inv = 1.0f / s;
    float4 o;
    o.x = e0 * inv; o.y = e1 * inv; o.z = e2 * inv; o.w = e3 * inv;
    *(float4*)&ga[row * (i64)Nv + tid * 4] = o;

    ushort4 ob;
    ob.x = f2bf(o.x); ob.y = f2bf(o.y); ob.z = f2bf(o.z); ob.w = f2bf(o.w);
    *(ushort4*)&gab[row * (i64)Nv + tid * 4] = ob;
}

// nodes f32 -> nodesb bf16 + X broadcast x4 (one read, five writes)
__global__ __launch_bounds__(256) void prep_k(const float* __restrict__ nodes,
                                              u16* __restrict__ nodesb,
                                              u16* __restrict__ Xb)
{
    const i64 i = (i64)blockIdx.x * 256 + threadIdx.x;  // over BND/4
    float4 v = ((const float4*)nodes)[i];
    ushort4 o;
    o.x = f2bf(v.x); o.y = f2bf(v.y); o.z = f2bf(v.z); o.w = f2bf(v.w);
    ((ushort4*)nodesb)[i] = o;
    const i64 q4 = BND / 4;
    #pragma unroll
    for (int h = 0; h < Hh; ++h) ((ushort4*)Xb)[(i64)h * q4 + i] = o;
}

// all weight transposes in one dispatch. z<3: Wq[e]; 3..5: Wk[e]; 6,7: gcnW;
// 8..11: Wagg 768-row slice. All 768x768 transposes.
__global__ __launch_bounds__(256) void trans_all(
    const float* __restrict__ Wq, const float* __restrict__ Wk,
    const float* __restrict__ gcnW, const float* __restrict__ Wagg,
    u16* __restrict__ wqkt, u16* __restrict__ gcnWt, u16* __restrict__ waggt)
{
    const int z = blockIdx.z;
    const i64 W768 = (i64)768 * 768;
    const float* src;
    u16* dst;
    int ldo;
    if (z < 3)      { src = Wq + z * W768;        dst = wqkt + z * W768;          ldo = 768; }
    else if (z < 6) { src = Wk + (z - 3) * W768;  dst = wqkt + (i64)z * W768;     ldo = 768; }
    else if (z < 8) { src = gcnW + (z - 6) * W768; dst = gcnWt + (i64)(z - 6) * W768; ldo = 768; }
    else            { src = Wagg + (i64)(z - 8) * W768; dst = waggt + (i64)(z - 8) * 768; ldo = 3072; }

    __shared__ u16 t[32][33];
    const int c0 = blockIdx.x * 32, r0 = blockIdx.y * 32;
    const int tx = threadIdx.x & 31, ty = threadIdx.x >> 5;
    #pragma unroll
    for (int i = ty; i < 32; i += 8)
        t[i][tx] = f2bf(src[(i64)(r0 + i) * 768 + c0 + tx]);
    __syncthreads();
    #pragma unroll
    for (int i = ty; i < 32; i += 8)
        dst[(i64)(c0 + i) * ldo + r0 + tx] = t[tx][i];
}

// out = p0 + p1 + bias (split-K reduce), float4 per thread
__global__ __launch_bounds__(256) void addbias_k(
    const float* __restrict__ p0, const float* __restrict__ p1,
    const float* __restrict__ bias, float* __restrict__ out)
{
    const i64 i4 = (i64)blockIdx.x * 256 + threadIdx.x;  // over BND/4
    const int nb = (int)((i4 * 4) % Dv);
    float4 a = ((const float4*)p0)[i4];
    float4 b = ((const float4*)p1)[i4];
    float4 bv = *(const float4*)&bias[nb];
    float4 o;
    o.x = a.x + b.x + bv.x; o.y = a.y + b.y + bv.y;
    o.z = a.z + b.z + bv.z; o.w = a.w + b.w + bv.w;
    ((float4*)out)[i4] = o;
}

// ---------------------------------------------------------------------------
extern "C" void kernel_launch(void* const* d_in, const int* in_sizes, int n_in,
                              void* d_out, int out_size, void* d_ws, size_t ws_size,
                              hipStream_t stream)
{
    const float* nodes = (const float*)d_in[0];
    const int*   adj   = (const int*)d_in[1];
    const float* Wq    = (const float*)d_in[2];
    const float* bq    = (const float*)d_in[3];
    const float* Wk    = (const float*)d_in[4];
    const float* bk    = (const float*)d_in[5];
    const float* gcnW  = (const float*)d_in[6];
    const float* gcnb  = (const float*)d_in[7];
    const float* Wagg  = (const float*)d_in[8];
    const float* bagg  = (const float*)d_in[9];

    float* out = (float*)d_out;             // (B,N,D) f32
    float* gaf = out + BND;                 // (H,B,N,N) f32

    const i64 W768 = (i64)768 * 768;
    u16* ws     = (u16*)d_ws;
    u16* qb     = ws;                       // 3*BND           (phase 1)
    u16* kb2    = ws + 3 * BND;             // 3*BND           (phase 1)
    u16* gab    = ws;                       // HBND bf16       (alias after scores)
    u16* nodesb = ws + 6 * BND;             // BND
    u16* gcnWt  = nodesb + BND;             // 2*W768
    u16* waggt  = gcnWt + 2 * W768;         // 4*W768
    u16* Xb     = waggt + 4 * W768;         // HBND
    u16* Htb    = Xb + HBND;                // HBND region, time-shared:
    u16* wqkt   = Htb;                      //   6*W768 (dead after q/k proj)
    u16* sbuf   = Htb;                      //   HBND (S bf16; dead after softmax)
    float* part = (float*)Htb;              //   2*BND f32 (final split-K)

    dim3 blk(256);

    prep_k<<<dim3((unsigned)(BND / 4 / 256)), blk, 0, stream>>>(nodes, nodesb, Xb);
    trans_all<<<dim3(24, 24, 12), blk, 0, stream>>>(Wq, Wk, gcnW, Wagg, wqkt, gcnWt, waggt);

    // fused q/k projections: z 0..2 -> q (bias bq), z 3..5 -> k (bias bk)
    gemm_bf16<1, false, 1, 6, 64, 6><<<dim3(2304), blk, 0, stream>>>(
        nodesb, 0, Dv, wqkt, W768, Dv, -1, bq, Dv, bk, qb, BND, Dv, Dv, 0);

    // fused masked scores -> S bf16 scratch (128n x 64m tiles)
    scores_mfma<<<dim3(4096), blk, 0, stream>>>(qb, kb2, adj, sbuf);

    // softmax: ga f32 (output) + P bf16 (gab aliases q/k, both dead now)
    softmax_k<<<dim3(Hh * Bv * Nv), blk, 0, stream>>>(sbuf, gaf, gab);

    for (int it = 0; it < 2; ++it) {
        if (it == 0) {
            // iter 0: X identical across heads -> H0^T = gcnW[0]^T @ nodes^T
            // (768 x 8192 only), Xupd indexes it by b = z&7.
            gemm_bf16<1, false, 0, 64, 6, 1><<<dim3(384), blk, 0, stream>>>(
                gcnWt, 0, Dv, nodesb, 0, Dv, -1, nullptr, 0, nullptr,
                Htb, 0, 8192, Dv, 0);
            gemm_bf16<2, false, 0, 6, 8, 32><<<dim3(1536), blk, 0, stream>>>(
                gab, (i64)Nv * Nv, Nv, Htb, 1024, 8192, 7, gcnb, 0, nullptr,
                Xb, (i64)Nv * Dv, Dv, Nv, 0);
        } else {
            // iter 1: full H^T = gcnW[1]^T @ X^T (768 x 32768)
            gemm_bf16<1, false, 0, 256, 6, 1><<<dim3(1536), blk, 0, stream>>>(
                gcnWt + W768, 0, Dv, Xb, 0, Dv, -1, nullptr, 0, nullptr,
                Htb, 0, 32768, Dv, 0);
            gemm_bf16<2, false, 0, 6, 8, 32><<<dim3(1536), blk, 0, stream>>>(
                gab, (i64)Nv * Nv, Nv, Htb, 1024, 32768, -1, gcnb + (i64)Dv, 0, nullptr,
                Xb, (i64)Nv * Dv, Dv, Nv, 0);
        }
    }

    // final: out = cat(X) @ W_agg + b_agg, split-K x2 into f32 partials
    gemm_bf16<0, true, 0, 6, 64, 2><<<dim3(768), blk, 0, stream>>>(
        Xb, 0, Dv, waggt, 0, Hh * Dv, -1, nullptr, 0, nullptr,
        part, BND, Dv, (Hh * Dv) / 2, (Hh * Dv) / 2);

    addbias_k<<<dim3((unsigned)(BND / 4 / 256)), blk, 0, stream>>>(
        part, part + BND, bagg, out);
}